// Round 8
// baseline (19361.920 us; speedup 1.0000x reference)
//
#include <hip/hip_runtime.h>
#include <math.h>

#define T_ALL 200
#define G     2048
#define H     512
#define PW    132
#define PX    128

typedef __attribute__((address_space(1))) const unsigned int g_u32;
typedef __attribute__((address_space(3))) unsigned int l_u32;

__device__ __forceinline__ void gl2lds16(const void* g, void* l) {
    __builtin_amdgcn_global_load_lds((g_u32*)g, (l_u32*)l, 16, 0, 0);
}

// Force a pointer into a VGPR so uniformity analysis can't route dependent
// loads through the scalar (s_load/K$) path. Same-address-per-lane vector
// loads coalesce to one L2 request per wave and pipeline via vmcnt.
__device__ __forceinline__ const float* vgpr_launder(const float* p) {
    asm volatile("" : "+v"(p));
    return p;
}

__device__ __forceinline__ float sigf(float x) { return 1.0f / (1.0f + expf(-x)); }

// proposals [b][t][c] -> xT[t][c/4][b] (float4 over c)
__global__ __launch_bounds__(256) void transpose_x(const float4* __restrict__ in,
                                                   float4* __restrict__ out) {
    const int t = blockIdx.x;
    const int b = threadIdx.x;
    #pragma unroll 4
    for (int cc = 0; cc < 32; ++cc) {
        out[((size_t)t * 32 + cc) * 256 + b] = in[((size_t)b * 200 + t) * 32 + cc];
    }
}

// Tiled fp32 GEMM: xp[tloc][r][b] = bias[r] + sum_k W[r][k] * x[t0+tloc][k][b]
__global__ __launch_bounds__(256, 2) void xproj_gemm(
    const float4* __restrict__ x, const float* __restrict__ W,
    const float* __restrict__ bih, const float* __restrict__ bhh,
    float* __restrict__ xp, int K4, int t0)
{
    __shared__ float wl[2][32 * PW];
    __shared__ float xl[2][32 * PX];
    const int tloc = blockIdx.x;
    const int bg   = blockIdx.y;
    const int rc   = blockIdx.z;
    const int tid  = threadIdx.x;
    const int K    = K4 * 4;
    const float4* xs = x + (size_t)(t0 + tloc) * K4 * 256;
    const int rbase = rc * 128;
    const int bbase = bg * 128;

    const int bcol = tid & 15;
    const int rrow = tid >> 4;
    const int b0 = 4 * bcol, r0 = 4 * rrow;

    const int wr  = tid >> 3;
    const int wkq = tid & 7;
    const int xb  = tid & 127;
    const int xk4 = tid >> 7;

    float acc[8][8];
    #pragma unroll
    for (int i = 0; i < 8; ++i)
        #pragma unroll
        for (int j = 0; j < 8; ++j) acc[i][j] = 0.f;

    const int nk = K4 >> 3;
    float4 wreg[4], xreg[4];

    #pragma unroll
    for (int j = 0; j < 4; ++j) {
        wreg[j] = *(const float4*)(W + (size_t)(rbase + wr + 32 * j) * K + wkq * 4);
        xreg[j] = xs[(size_t)(xk4 + 2 * j) * 256 + bbase + xb];
    }
    #pragma unroll
    for (int j = 0; j < 4; ++j) {
        #pragma unroll
        for (int i = 0; i < 4; ++i) {
            wl[0][(wkq * 4 + i) * PW + wr + 32 * j] = ((const float*)&wreg[j])[i];
            xl[0][((xk4 + 2 * j) * 4 + i) * PX + xb] = ((const float*)&xreg[j])[i];
        }
    }
    __syncthreads();

    for (int ro = 0; ro < nk; ++ro) {
        if (ro + 1 < nk) {
            const int k0 = (ro + 1) * 32;
            #pragma unroll
            for (int j = 0; j < 4; ++j) {
                wreg[j] = *(const float4*)(W + (size_t)(rbase + wr + 32 * j) * K + k0 + wkq * 4);
                xreg[j] = xs[(size_t)(k0 / 4 + xk4 + 2 * j) * 256 + bbase + xb];
            }
        }
        const float* wlb = wl[ro & 1];
        const float* xlb = xl[ro & 1];
        #pragma unroll 2
        for (int k = 0; k < 32; ++k) {
            const float4 w0 = *(const float4*)&wlb[k * PW + r0];
            const float4 w1 = *(const float4*)&wlb[k * PW + r0 + 64];
            const float4 v0 = *(const float4*)&xlb[k * PX + b0];
            const float4 v1 = *(const float4*)&xlb[k * PX + b0 + 64];
            const float wf[8] = {w0.x, w0.y, w0.z, w0.w, w1.x, w1.y, w1.z, w1.w};
            const float xf[8] = {v0.x, v0.y, v0.z, v0.w, v1.x, v1.y, v1.z, v1.w};
            #pragma unroll
            for (int i = 0; i < 8; ++i)
                #pragma unroll
                for (int j = 0; j < 8; ++j)
                    acc[i][j] += wf[i] * xf[j];
        }
        __syncthreads();
        if (ro + 1 < nk) {
            const int nb = (ro + 1) & 1;
            #pragma unroll
            for (int j = 0; j < 4; ++j) {
                #pragma unroll
                for (int i = 0; i < 4; ++i) {
                    wl[nb][(wkq * 4 + i) * PW + wr + 32 * j] = ((const float*)&wreg[j])[i];
                    xl[nb][((xk4 + 2 * j) * 4 + i) * PX + xb] = ((const float*)&xreg[j])[i];
                }
            }
            __syncthreads();
        }
    }

    #pragma unroll
    for (int ii = 0; ii < 8; ++ii) {
        const int rl = (ii < 4) ? (r0 + ii) : (r0 + 60 + ii);
        const int gr = rbase + rl;
        const float bias = bih[gr] + bhh[gr];
        float* o = xp + ((size_t)tloc * G + gr) * 256 + bbase;
        float4 u0 = {acc[ii][0] + bias, acc[ii][1] + bias, acc[ii][2] + bias, acc[ii][3] + bias};
        float4 u1 = {acc[ii][4] + bias, acc[ii][5] + bias, acc[ii][6] + bias, acc[ii][7] + bias};
        *(float4*)(o + b0) = u0;
        *(float4*)(o + b0 + 64) = u1;
    }
}

// One fused superstep per dispatch (dispatch boundary = barrier). Weights are
// read via VGPR-laundered pointers -> vector global_load path (1 coalesced
// request per wave, deep vmcnt pipelining, L1 line reuse) instead of the
// scalar K$ path, which serialized ~3K cold L3 misses per CU per step.
__global__ __launch_bounds__(512, 2) void lstm_step(
    const float* __restrict__ xp0, const float* __restrict__ Whh0,
    const float* __restrict__ Wih1, const float* __restrict__ Whh1,
    const float* __restrict__ bih1, const float* __restrict__ bhh1,
    float4* __restrict__ h0buf, float4* __restrict__ h1buf,
    float* __restrict__ cb0, float* __restrict__ cb1,
    int t, int tloc)
{
    __shared__ float4 hs[2][2048];   // 2 x 32 KB double buffer
    const int tid  = threadIdx.x;
    const int wv   = tid >> 6;       // 0..7
    const int lane = tid & 63;
    const int f    = blockIdx.x;     // 0..255
    const int jj   = f >> 3;
    const int bg   = jj & 3;                 // batch group (64 batches)
    const int hg   = (f & 7) + 8 * (jj >> 2);// hid group 0..63
    const int bG   = bg * 64 + lane;
    const int hid  = __builtin_amdgcn_readfirstlane(hg * 8 + wv);

    const float *w0[4], *wi[4], *w1[4];
    float bs1[4];
    #pragma unroll
    for (int q = 0; q < 4; ++q) {
        const int r = q * H + hid;
        w0[q] = vgpr_launder(Whh0 + (size_t)r * H);
        wi[q] = vgpr_launder(Wih1 + (size_t)r * H);
        w1[q] = vgpr_launder(Whh1 + (size_t)r * H);
        bs1[q] = bih1[r] + bhh1[r];
    }

    float a0[4], a1[4];
    if (t < T_ALL) {
        #pragma unroll
        for (int q = 0; q < 4; ++q)
            a0[q] = xp0[((size_t)tloc * G + q * H + hid) * 256 + bG];
    } else {
        #pragma unroll
        for (int q = 0; q < 4; ++q) a0[q] = 0.f;
    }
    #pragma unroll
    for (int q = 0; q < 4; ++q) a1[q] = bs1[q];

    if (t >= 1) {
        const float4* hin0 = h0buf + (size_t)((t - 1) & 1) * 32768;
        const float4* hin1 = h1buf + (size_t)((t - 2) & 1) * 32768;
        const int nro = (t >= 2) ? 8 : 4;
        #pragma unroll
        for (int s = 0; s < 4; ++s) {
            const int kk = wv + 8 * s;
            gl2lds16(hin0 + (size_t)kk * 256 + bG, &hs[0][kk * 64]);
        }
        __syncthreads();
        for (int ro = 0; ro < nro; ++ro) {
            if (ro + 1 < nro) {
                const float4* src = (ro + 1 < 4)
                    ? hin0 + (size_t)((ro + 1) * 32) * 256
                    : hin1 + (size_t)((ro - 3) * 32) * 256;
                #pragma unroll
                for (int s = 0; s < 4; ++s) {
                    const int kk = wv + 8 * s;
                    gl2lds16(src + (size_t)kk * 256 + bG, &hs[(ro + 1) & 1][kk * 64]);
                }
            }
            const float4* hb = hs[ro & 1];
            if (ro < 4) {
                const int kb = ro * 128;
                #pragma unroll 4
                for (int kk = 0; kk < 32; ++kk) {
                    const float4 v = hb[kk * 64 + lane];
                    const int ko = kb + kk * 4;
                    #pragma unroll
                    for (int q = 0; q < 4; ++q) {
                        const float4 w = *(const float4*)(w0[q] + ko);
                        a0[q] += w.x*v.x + w.y*v.y + w.z*v.z + w.w*v.w;
                        const float4 u = *(const float4*)(wi[q] + ko);
                        a1[q] += u.x*v.x + u.y*v.y + u.z*v.z + u.w*v.w;
                    }
                }
            } else {
                const int kb = (ro - 4) * 128;
                #pragma unroll 4
                for (int kk = 0; kk < 32; ++kk) {
                    const float4 v = hb[kk * 64 + lane];
                    const int ko = kb + kk * 4;
                    #pragma unroll
                    for (int q = 0; q < 4; ++q) {
                        const float4 w = *(const float4*)(w1[q] + ko);
                        a1[q] += w.x*v.x + w.y*v.y + w.z*v.z + w.w*v.w;
                    }
                }
            }
            __syncthreads();
        }
    }

    if (t < T_ALL) {
        float c0 = (t > 0) ? cb0[(size_t)hid * 256 + bG] : 0.f;
        float* hw = (float*)(h0buf + (size_t)(t & 1) * 32768);
        const float ig = sigf(a0[0]), fg = sigf(a0[1]);
        const float gg = tanhf(a0[2]), og = sigf(a0[3]);
        c0 = fg * c0 + ig * gg;
        hw[(((hid >> 2) * 256) + bG) * 4 + (hid & 3)] = og * tanhf(c0);
        cb0[(size_t)hid * 256 + bG] = c0;
    }
    if (t >= 1) {
        float c1 = (t > 1) ? cb1[(size_t)hid * 256 + bG] : 0.f;
        float* hw = (float*)(h1buf + (size_t)((t - 1) & 1) * 32768);
        const float ig = sigf(a1[0]), fg = sigf(a1[1]);
        const float gg = tanhf(a1[2]), og = sigf(a1[3]);
        c1 = fg * c1 + ig * gg;
        hw[(((hid >> 2) * 256) + bG) * 4 + (hid & 3)] = og * tanhf(c1);
        cb1[(size_t)hid * 256 + bG] = c1;
    }
}

// heads: base[k/4][b][4k] -> cls (256x40), bbox (256x2), 2 zero scalars
__global__ __launch_bounds__(64) void heads(
    const float4* __restrict__ base, const float4* __restrict__ clsW,
    const float* __restrict__ clsb, const float4* __restrict__ bbW,
    const float* __restrict__ bbb, float* __restrict__ out)
{
    const int b = blockIdx.x;
    const int j = threadIdx.x;
    if (j < 42) {
        const float4* w = (j < 40) ? (clsW + (size_t)j * 128) : (bbW + (size_t)(j - 40) * 128);
        float acc = 0.f;
        #pragma unroll 4
        for (int kk = 0; kk < 128; ++kk) {
            const float4 bv = base[(size_t)kk * 256 + b];
            const float4 wv = w[kk];
            acc += bv.x*wv.x + bv.y*wv.y + bv.z*wv.z + bv.w*wv.w;
        }
        if (j < 40) out[(size_t)b * 40 + j] = acc + clsb[j];
        else        out[10240 + (size_t)b * 2 + (j - 40)] = acc + bbb[j - 40];
    }
    if (b == 0 && (j == 62 || j == 63)) out[10752 + (j - 62)] = 0.f;
}

extern "C" void kernel_launch(void* const* d_in, const int* in_sizes, int n_in,
                              void* d_out, int out_size, void* d_ws, size_t ws_size,
                              hipStream_t stream) {
    const float* proposals = (const float*)d_in[2];
    const float* Wih0 = (const float*)d_in[4];
    const float* Whh0 = (const float*)d_in[5];
    const float* bih0 = (const float*)d_in[6];
    const float* bhh0 = (const float*)d_in[7];
    const float* Wih1 = (const float*)d_in[8];
    const float* Whh1 = (const float*)d_in[9];
    const float* bih1 = (const float*)d_in[10];
    const float* bhh1 = (const float*)d_in[11];
    const float* clsW = (const float*)d_in[12];
    const float* clsb = (const float*)d_in[13];
    const float* bbW  = (const float*)d_in[14];
    const float* bbb  = (const float*)d_in[15];

    char* ws = (char*)d_ws;
    const size_t XT_B = 200ull * 32 * 256 * 16;   // 26,214,400
    const size_t HB_B = 2ull * 32768 * 16;        // 1,048,576 per layer ping-pong
    const size_t C_B  = 512ull * 256 * 4;         // 524,288 per layer
    const size_t XP_T = (size_t)G * 256 * 4;      // 2,097,152 per layer0 step
    const size_t base = XT_B + 2 * HB_B + 2 * C_B;

    long long avail = (long long)ws_size - (long long)base;
    int TC = avail > 0 ? (int)(avail / (long long)XP_T) : 1;
    if (TC > T_ALL) TC = T_ALL;
    if (TC < 1) TC = 1;

    float4* xT  = (float4*)ws;
    float4* h0b = (float4*)(ws + XT_B);
    float4* h1b = (float4*)(ws + XT_B + HB_B);
    float*  cb0 = (float*)(ws + XT_B + 2 * HB_B);
    float*  cb1 = (float*)(ws + XT_B + 2 * HB_B + C_B);
    float*  xp0 = (float*)(ws + base);

    transpose_x<<<200, 256, 0, stream>>>((const float4*)proposals, xT);

    for (int t0 = 0; t0 < T_ALL + 1; t0 += TC) {
        const int t1 = (t0 + TC < T_ALL + 1) ? (t0 + TC) : (T_ALL + 1);
        const int lim = (t1 < T_ALL) ? t1 : T_ALL;
        const int len0 = lim - t0;                 // layer0 steps needing xp
        if (len0 > 0)
            xproj_gemm<<<dim3(len0, 2, 16), 256, 0, stream>>>(xT, Wih0, bih0, bhh0,
                                                              xp0, 32, t0);
        for (int t = t0; t < t1; ++t)
            lstm_step<<<256, 512, 0, stream>>>(xp0, Whh0, Wih1, Whh1, bih1, bhh1,
                                               h0b, h1b, cb0, cb1,
                                               t, (t < T_ALL) ? (t - t0) : 0);
    }

    // base_feat = h1 slot (199 & 1) = 1
    heads<<<256, 64, 0, stream>>>((const float4*)(h1b + 32768), (const float4*)clsW,
                                  clsb, (const float4*)bbW, bbb, (float*)d_out);
}

// Round 9
// 18147.476 us; speedup vs baseline: 1.0669x; 1.0669x over previous
//
#include <hip/hip_runtime.h>
#include <math.h>

#define T_ALL 200
#define G     2048
#define H     512
#define PW    132
#define PX    128

typedef __attribute__((address_space(1))) const unsigned int g_u32;
typedef __attribute__((address_space(3))) unsigned int l_u32;

__device__ __forceinline__ void gl2lds16(const void* g, void* l) {
    __builtin_amdgcn_global_load_lds((g_u32*)g, (l_u32*)l, 16, 0, 0);
}

__device__ __forceinline__ float sigf(float x) { return 1.0f / (1.0f + expf(-x)); }

// proposals [b][t][c] -> xT[t][c/4][b] (float4 over c)
__global__ __launch_bounds__(256) void transpose_x(const float4* __restrict__ in,
                                                   float4* __restrict__ out) {
    const int t = blockIdx.x;
    const int b = threadIdx.x;
    #pragma unroll 4
    for (int cc = 0; cc < 32; ++cc) {
        out[((size_t)t * 32 + cc) * 256 + b] = in[((size_t)b * 200 + t) * 32 + cc];
    }
}

// Tiled fp32 GEMM: xp[tloc][r][b] = bias[r] + sum_k W[r][k] * x[t0+tloc][k][b]
__global__ __launch_bounds__(256, 2) void xproj_gemm(
    const float4* __restrict__ x, const float* __restrict__ W,
    const float* __restrict__ bih, const float* __restrict__ bhh,
    float* __restrict__ xp, int K4, int t0)
{
    __shared__ float wl[2][32 * PW];
    __shared__ float xl[2][32 * PX];
    const int tloc = blockIdx.x;
    const int bg   = blockIdx.y;
    const int rc   = blockIdx.z;
    const int tid  = threadIdx.x;
    const int K    = K4 * 4;
    const float4* xs = x + (size_t)(t0 + tloc) * K4 * 256;
    const int rbase = rc * 128;
    const int bbase = bg * 128;

    const int bcol = tid & 15;
    const int rrow = tid >> 4;
    const int b0 = 4 * bcol, r0 = 4 * rrow;

    const int wr  = tid >> 3;
    const int wkq = tid & 7;
    const int xb  = tid & 127;
    const int xk4 = tid >> 7;

    float acc[8][8];
    #pragma unroll
    for (int i = 0; i < 8; ++i)
        #pragma unroll
        for (int j = 0; j < 8; ++j) acc[i][j] = 0.f;

    const int nk = K4 >> 3;
    float4 wreg[4], xreg[4];

    #pragma unroll
    for (int j = 0; j < 4; ++j) {
        wreg[j] = *(const float4*)(W + (size_t)(rbase + wr + 32 * j) * K + wkq * 4);
        xreg[j] = xs[(size_t)(xk4 + 2 * j) * 256 + bbase + xb];
    }
    #pragma unroll
    for (int j = 0; j < 4; ++j) {
        #pragma unroll
        for (int i = 0; i < 4; ++i) {
            wl[0][(wkq * 4 + i) * PW + wr + 32 * j] = ((const float*)&wreg[j])[i];
            xl[0][((xk4 + 2 * j) * 4 + i) * PX + xb] = ((const float*)&xreg[j])[i];
        }
    }
    __syncthreads();

    for (int ro = 0; ro < nk; ++ro) {
        if (ro + 1 < nk) {
            const int k0 = (ro + 1) * 32;
            #pragma unroll
            for (int j = 0; j < 4; ++j) {
                wreg[j] = *(const float4*)(W + (size_t)(rbase + wr + 32 * j) * K + k0 + wkq * 4);
                xreg[j] = xs[(size_t)(k0 / 4 + xk4 + 2 * j) * 256 + bbase + xb];
            }
        }
        const float* wlb = wl[ro & 1];
        const float* xlb = xl[ro & 1];
        #pragma unroll 2
        for (int k = 0; k < 32; ++k) {
            const float4 w0 = *(const float4*)&wlb[k * PW + r0];
            const float4 w1 = *(const float4*)&wlb[k * PW + r0 + 64];
            const float4 v0 = *(const float4*)&xlb[k * PX + b0];
            const float4 v1 = *(const float4*)&xlb[k * PX + b0 + 64];
            const float wf[8] = {w0.x, w0.y, w0.z, w0.w, w1.x, w1.y, w1.z, w1.w};
            const float xf[8] = {v0.x, v0.y, v0.z, v0.w, v1.x, v1.y, v1.z, v1.w};
            #pragma unroll
            for (int i = 0; i < 8; ++i)
                #pragma unroll
                for (int j = 0; j < 8; ++j)
                    acc[i][j] += wf[i] * xf[j];
        }
        __syncthreads();
        if (ro + 1 < nk) {
            const int nb = (ro + 1) & 1;
            #pragma unroll
            for (int j = 0; j < 4; ++j) {
                #pragma unroll
                for (int i = 0; i < 4; ++i) {
                    wl[nb][(wkq * 4 + i) * PW + wr + 32 * j] = ((const float*)&wreg[j])[i];
                    xl[nb][((xk4 + 2 * j) * 4 + i) * PX + xb] = ((const float*)&xreg[j])[i];
                }
            }
            __syncthreads();
        }
    }

    #pragma unroll
    for (int ii = 0; ii < 8; ++ii) {
        const int rl = (ii < 4) ? (r0 + ii) : (r0 + 60 + ii);
        const int gr = rbase + rl;
        const float bias = bih[gr] + bhh[gr];
        float* o = xp + ((size_t)tloc * G + gr) * 256 + bbase;
        float4 u0 = {acc[ii][0] + bias, acc[ii][1] + bias, acc[ii][2] + bias, acc[ii][3] + bias};
        float4 u1 = {acc[ii][4] + bias, acc[ii][5] + bias, acc[ii][6] + bias, acc[ii][7] + bias};
        *(float4*)(o + b0) = u0;
        *(float4*)(o + b0 + 64) = u1;
    }
}

// One fused superstep per dispatch (dispatch boundary = barrier). Weight reads
// use the scalar (s_load) path as in R7, but the block's 192 KB weight
// footprint is first TOUCHED with per-lane-coalesced vector loads to warm the
// (dispatch-invalidated) L2, so the shallow-concurrency scalar misses hit
// ~150-cyc L2 instead of serialized ~600-900-cyc L3.
__global__ __launch_bounds__(512, 2) void lstm_step(
    const float* __restrict__ xp0, const float* __restrict__ Whh0,
    const float* __restrict__ Wih1, const float* __restrict__ Whh1,
    const float* __restrict__ bih1, const float* __restrict__ bhh1,
    float4* __restrict__ h0buf, float4* __restrict__ h1buf,
    float* __restrict__ cb0, float* __restrict__ cb1,
    float* __restrict__ sink, int t, int tloc)
{
    __shared__ float4 hs[2][2048];   // 2 x 32 KB double buffer
    const int tid  = threadIdx.x;
    const int wv   = tid >> 6;       // 0..7
    const int lane = tid & 63;
    const int f    = blockIdx.x;     // 0..255
    const int jj   = f >> 3;
    const int bg   = jj & 3;                 // batch group (64 batches)
    const int hg   = (f & 7) + 8 * (jj >> 2);// hid group 0..63
    const int bG   = bg * 64 + lane;
    const int hid  = __builtin_amdgcn_readfirstlane(hg * 8 + wv);

    // ---- L2 warm-up: touch this block's weight footprint (12 chunks of
    // 16 KB = 8 consecutive rows each) via coalesced vector loads. ----
    float4 ta[8];
    #pragma unroll
    for (int j = 0; j < 8; ++j) ta[j] = make_float4(0.f, 0.f, 0.f, 0.f);
    {
        const float* mats[3] = {Whh0, Wih1, Whh1};
        #pragma unroll
        for (int m = 0; m < 3; ++m)
            #pragma unroll
            for (int q = 0; q < 4; ++q) {
                const float4* cb =
                    (const float4*)(mats[m] + (size_t)(q * H + hg * 8) * H);
                const int i0 = (m * 4 + q) & 7;
                const float4 v0 = cb[tid];
                const float4 v1 = cb[tid + 512];
                ta[i0].x += v0.x; ta[i0].y += v0.y;
                ta[i0].z += v0.z; ta[i0].w += v0.w;
                ta[(i0 + 4) & 7].x += v1.x; ta[(i0 + 4) & 7].y += v1.y;
                ta[(i0 + 4) & 7].z += v1.z; ta[(i0 + 4) & 7].w += v1.w;
            }
    }

    const float *w0[4], *wi[4], *w1[4];
    float bs1[4];
    #pragma unroll
    for (int q = 0; q < 4; ++q) {
        const int r = q * H + hid;
        w0[q] = Whh0 + (size_t)r * H;
        wi[q] = Wih1 + (size_t)r * H;
        w1[q] = Whh1 + (size_t)r * H;
        bs1[q] = bih1[r] + bhh1[r];
    }

    float a0[4], a1[4];
    if (t < T_ALL) {
        #pragma unroll
        for (int q = 0; q < 4; ++q)
            a0[q] = xp0[((size_t)tloc * G + q * H + hid) * 256 + bG];
    } else {
        #pragma unroll
        for (int q = 0; q < 4; ++q) a0[q] = 0.f;
    }
    #pragma unroll
    for (int q = 0; q < 4; ++q) a1[q] = bs1[q];

    if (t >= 1) {
        const float4* hin0 = h0buf + (size_t)((t - 1) & 1) * 32768;
        const float4* hin1 = h1buf + (size_t)((t - 2) & 1) * 32768;
        const int nro = (t >= 2) ? 8 : 4;
        #pragma unroll
        for (int s = 0; s < 4; ++s) {
            const int kk = wv + 8 * s;
            gl2lds16(hin0 + (size_t)kk * 256 + bG, &hs[0][kk * 64]);
        }
        __syncthreads();
        for (int ro = 0; ro < nro; ++ro) {
            if (ro + 1 < nro) {
                const float4* src = (ro + 1 < 4)
                    ? hin0 + (size_t)((ro + 1) * 32) * 256
                    : hin1 + (size_t)((ro - 3) * 32) * 256;
                #pragma unroll
                for (int s = 0; s < 4; ++s) {
                    const int kk = wv + 8 * s;
                    gl2lds16(src + (size_t)kk * 256 + bG, &hs[(ro + 1) & 1][kk * 64]);
                }
            }
            const float4* hb = hs[ro & 1];
            if (ro < 4) {
                const int kb = ro * 128;
                #pragma unroll 4
                for (int kk = 0; kk < 32; ++kk) {
                    const float4 v = hb[kk * 64 + lane];
                    const int ko = kb + kk * 4;
                    #pragma unroll
                    for (int q = 0; q < 4; ++q) {
                        const float4 w = *(const float4*)(w0[q] + ko);
                        a0[q] += w.x*v.x + w.y*v.y + w.z*v.z + w.w*v.w;
                        const float4 u = *(const float4*)(wi[q] + ko);
                        a1[q] += u.x*v.x + u.y*v.y + u.z*v.z + u.w*v.w;
                    }
                }
            } else {
                const int kb = (ro - 4) * 128;
                #pragma unroll 4
                for (int kk = 0; kk < 32; ++kk) {
                    const float4 v = hb[kk * 64 + lane];
                    const int ko = kb + kk * 4;
                    #pragma unroll
                    for (int q = 0; q < 4; ++q) {
                        const float4 w = *(const float4*)(w1[q] + ko);
                        a1[q] += w.x*v.x + w.y*v.y + w.z*v.z + w.w*v.w;
                    }
                }
            }
            __syncthreads();
        }
    }

    if (t < T_ALL) {
        float c0 = (t > 0) ? cb0[(size_t)hid * 256 + bG] : 0.f;
        float* hw = (float*)(h0buf + (size_t)(t & 1) * 32768);
        const float ig = sigf(a0[0]), fg = sigf(a0[1]);
        const float gg = tanhf(a0[2]), og = sigf(a0[3]);
        c0 = fg * c0 + ig * gg;
        hw[(((hid >> 2) * 256) + bG) * 4 + (hid & 3)] = og * tanhf(c0);
        cb0[(size_t)hid * 256 + bG] = c0;
    }
    if (t >= 1) {
        float c1 = (t > 1) ? cb1[(size_t)hid * 256 + bG] : 0.f;
        float* hw = (float*)(h1buf + (size_t)((t - 1) & 1) * 32768);
        const float ig = sigf(a1[0]), fg = sigf(a1[1]);
        const float gg = tanhf(a1[2]), og = sigf(a1[3]);
        c1 = fg * c1 + ig * gg;
        hw[(((hid >> 2) * 256) + bG) * 4 + (hid & 3)] = og * tanhf(c1);
        cb1[(size_t)hid * 256 + bG] = c1;
    }

    // consume the warm-up loads so they are not dead-code-eliminated
    float ts = 0.f;
    #pragma unroll
    for (int j = 0; j < 8; ++j) ts += ta[j].x + ta[j].y + ta[j].z + ta[j].w;
    if (tid == 0) sink[f] = ts;
}

// heads: base[k/4][b][4k] -> cls (256x40), bbox (256x2), 2 zero scalars
__global__ __launch_bounds__(64) void heads(
    const float4* __restrict__ base, const float4* __restrict__ clsW,
    const float* __restrict__ clsb, const float4* __restrict__ bbW,
    const float* __restrict__ bbb, float* __restrict__ out)
{
    const int b = blockIdx.x;
    const int j = threadIdx.x;
    if (j < 42) {
        const float4* w = (j < 40) ? (clsW + (size_t)j * 128) : (bbW + (size_t)(j - 40) * 128);
        float acc = 0.f;
        #pragma unroll 4
        for (int kk = 0; kk < 128; ++kk) {
            const float4 bv = base[(size_t)kk * 256 + b];
            const float4 wv = w[kk];
            acc += bv.x*wv.x + bv.y*wv.y + bv.z*wv.z + bv.w*wv.w;
        }
        if (j < 40) out[(size_t)b * 40 + j] = acc + clsb[j];
        else        out[10240 + (size_t)b * 2 + (j - 40)] = acc + bbb[j - 40];
    }
    if (b == 0 && (j == 62 || j == 63)) out[10752 + (j - 62)] = 0.f;
}

extern "C" void kernel_launch(void* const* d_in, const int* in_sizes, int n_in,
                              void* d_out, int out_size, void* d_ws, size_t ws_size,
                              hipStream_t stream) {
    const float* proposals = (const float*)d_in[2];
    const float* Wih0 = (const float*)d_in[4];
    const float* Whh0 = (const float*)d_in[5];
    const float* bih0 = (const float*)d_in[6];
    const float* bhh0 = (const float*)d_in[7];
    const float* Wih1 = (const float*)d_in[8];
    const float* Whh1 = (const float*)d_in[9];
    const float* bih1 = (const float*)d_in[10];
    const float* bhh1 = (const float*)d_in[11];
    const float* clsW = (const float*)d_in[12];
    const float* clsb = (const float*)d_in[13];
    const float* bbW  = (const float*)d_in[14];
    const float* bbb  = (const float*)d_in[15];

    char* ws = (char*)d_ws;
    const size_t XT_B  = 200ull * 32 * 256 * 16;   // 26,214,400
    const size_t HB_B  = 2ull * 32768 * 16;        // 1,048,576 per layer ping-pong
    const size_t C_B   = 512ull * 256 * 4;         // 524,288 per layer
    const size_t SNK_B = 1024;                     // touch-sum sink (256 floats)
    const size_t XP_T  = (size_t)G * 256 * 4;      // 2,097,152 per layer0 step
    const size_t base  = XT_B + 2 * HB_B + 2 * C_B + SNK_B;

    long long avail = (long long)ws_size - (long long)base;
    int TC = avail > 0 ? (int)(avail / (long long)XP_T) : 1;
    if (TC > T_ALL) TC = T_ALL;
    if (TC < 1) TC = 1;

    float4* xT  = (float4*)ws;
    float4* h0b = (float4*)(ws + XT_B);
    float4* h1b = (float4*)(ws + XT_B + HB_B);
    float*  cb0 = (float*)(ws + XT_B + 2 * HB_B);
    float*  cb1 = (float*)(ws + XT_B + 2 * HB_B + C_B);
    float*  snk = (float*)(ws + XT_B + 2 * HB_B + 2 * C_B);
    float*  xp0 = (float*)(ws + base);

    transpose_x<<<200, 256, 0, stream>>>((const float4*)proposals, xT);

    for (int t0 = 0; t0 < T_ALL + 1; t0 += TC) {
        const int t1 = (t0 + TC < T_ALL + 1) ? (t0 + TC) : (T_ALL + 1);
        const int lim = (t1 < T_ALL) ? t1 : T_ALL;
        const int len0 = lim - t0;                 // layer0 steps needing xp
        if (len0 > 0)
            xproj_gemm<<<dim3(len0, 2, 16), 256, 0, stream>>>(xT, Wih0, bih0, bhh0,
                                                              xp0, 32, t0);
        for (int t = t0; t < t1; ++t)
            lstm_step<<<256, 512, 0, stream>>>(xp0, Whh0, Wih1, Whh1, bih1, bhh1,
                                               h0b, h1b, cb0, cb1, snk,
                                               t, (t < T_ALL) ? (t - t0) : 0);
    }

    // base_feat = h1 slot (199 & 1) = 1
    heads<<<256, 64, 0, stream>>>((const float4*)(h1b + 32768), (const float4*)clsW,
                                  clsb, (const float4*)bbW, bbb, (float*)d_out);
}

// Round 10
// 4585.610 us; speedup vs baseline: 4.2223x; 3.9575x over previous
//
#include <hip/hip_runtime.h>
#include <math.h>

#define T_ALL 200

typedef __attribute__((ext_vector_type(8)))  short v8s;
typedef __attribute__((ext_vector_type(16))) float v16f;

__device__ __forceinline__ unsigned short f2bf(float f) {
    unsigned int u = __float_as_uint(f);
    u += 0x7FFF + ((u >> 16) & 1);          // round-to-nearest-even
    return (unsigned short)(u >> 16);
}
__device__ __forceinline__ float bf2f(unsigned short s) {
    return __uint_as_float(((unsigned int)s) << 16);
}
__device__ __forceinline__ float sigf(float x) { return 1.0f / (1.0f + expf(-x)); }

// ---- ws layout (bytes) ----
// Apack: 6656 frags x 1KB per plane. frag ranges: mx[0,512) m0[512,2560) mi[2560,4608) m1[4608,6656)
#define A_FRAGS   6656ULL
#define A_HI_OFF  0ULL
#define A_LO_OFF  (A_FRAGS * 1024ULL)                    //  6,815,744
#define X_HI_OFF  (2ULL * A_FRAGS * 1024ULL)             // 13,631,488
#define X_BYTES   (200ULL * 256 * 128 * 2)               // 13,107,200
#define X_LO_OFF  (X_HI_OFF + X_BYTES)
#define H_BYTES   (2ULL * 256 * 512 * 2)                 // 524,288 per plane (2 slots)
#define HHI0_OFF  (X_LO_OFF + X_BYTES)
#define HLO0_OFF  (HHI0_OFF + H_BYTES)
#define HHI1_OFF  (HLO0_OFF + H_BYTES)
#define HLO1_OFF  (HHI1_OFF + H_BYTES)
#define CB0_OFF   (HLO1_OFF + H_BYTES)
#define CB_BYTES  (512ULL * 256 * 4)
#define CB1_OFF   (CB0_OFF + CB_BYTES)
#define B0PK_OFF  (CB1_OFF + CB_BYTES)
#define B1PK_OFF  (B0PK_OFF + 8192ULL)

// Pack W rows into MFMA 32x32x16 A-fragment order, bf16 hi/lo planes.
// Block row order m = hl*4 + q (hl = hid-local 0..7, q = gate) -> global row q*512 + hg*8 + hl.
// Frag (fi, lane): A[m = lane&31][k = c*16 + (lane>>5)*8 + j], j=0..7.
__global__ __launch_bounds__(64) void pack_w(
    const float* __restrict__ Wih0, const float* __restrict__ Whh0,
    const float* __restrict__ Wih1, const float* __restrict__ Whh1,
    unsigned short* __restrict__ Ahi, unsigned short* __restrict__ Alo)
{
    const int fi = blockIdx.x, lane = threadIdx.x;
    const float* W; int K, hg, c;
    if (fi < 512)       { W = Wih0; K = 128; hg = fi >> 3;          c = fi & 7;          }
    else if (fi < 2560) { W = Whh0; K = 512; hg = (fi - 512) >> 5;  c = (fi - 512) & 31; }
    else if (fi < 4608) { W = Wih1; K = 512; hg = (fi - 2560) >> 5; c = (fi - 2560) & 31;}
    else                { W = Whh1; K = 512; hg = (fi - 4608) >> 5; c = (fi - 4608) & 31;}
    const int m = lane & 31, half = lane >> 5;
    const int q = m & 3, hl = m >> 2;
    const int r = q * 512 + hg * 8 + hl;
    const int k0 = c * 16 + half * 8;
    const float* src = W + (size_t)r * K + k0;
    unsigned short* dh = Ahi + (size_t)fi * 512 + lane * 8;
    unsigned short* dl = Alo + (size_t)fi * 512 + lane * 8;
    #pragma unroll
    for (int j = 0; j < 8; ++j) {
        const float w = src[j];
        const unsigned short h = f2bf(w);
        dh[j] = h;
        dl[j] = f2bf(w - bf2f(h));
    }
}

// proposals [b][t][c] fp32 -> xHi/xLo [t][b][c] bf16
__global__ __launch_bounds__(256) void prep_x(const float* __restrict__ prop,
                                              unsigned short* __restrict__ xHi,
                                              unsigned short* __restrict__ xLo)
{
    const int t = blockIdx.x, b = threadIdx.x;
    const float* src = prop + ((size_t)b * 200 + t) * 128;
    unsigned short* dh = xHi + ((size_t)t * 256 + b) * 128;
    unsigned short* dl = xLo + ((size_t)t * 256 + b) * 128;
    #pragma unroll 4
    for (int c = 0; c < 128; ++c) {
        const float f = src[c];
        const unsigned short h = f2bf(f);
        dh[c] = h;
        dl[c] = f2bf(f - bf2f(h));
    }
}

// bias packs: b0pk[hid] = float4 over gates (i,f,g,o)
__global__ __launch_bounds__(512) void pack_bias(
    const float* __restrict__ bih0, const float* __restrict__ bhh0,
    const float* __restrict__ bih1, const float* __restrict__ bhh1,
    float4* __restrict__ b0, float4* __restrict__ b1)
{
    const int hid = threadIdx.x;
    float4 u, v;
    u.x = bih0[hid] + bhh0[hid];
    u.y = bih0[512 + hid] + bhh0[512 + hid];
    u.z = bih0[1024 + hid] + bhh0[1024 + hid];
    u.w = bih0[1536 + hid] + bhh0[1536 + hid];
    v.x = bih1[hid] + bhh1[hid];
    v.y = bih1[512 + hid] + bhh1[512 + hid];
    v.z = bih1[1024 + hid] + bhh1[1024 + hid];
    v.w = bih1[1536 + hid] + bhh1[1536 + hid];
    b0[hid] = u; b1[hid] = v;
}

// One fused superstep per dispatch, MFMA-based (split-bf16 hi/lo, 4 products =
// fp32-level precision). 256 blocks x 512 threads. Block = 8 hids x 64 batches.
// Wave (wv) = (matvec mv = wv>>1, batch-half nt = wv&1); one 32x32x16 C-tile per
// wave. mv: 0 = Wih0*x[t] (K=128), 1 = Whh0*h0[t-1], 2 = Wih1*h0[t-1],
// 3 = Whh1*h1[t-2] (K=512 each). mx/mi C-tiles pass through LDS to m0/m1 waves,
// which do the in-thread LSTM update (C layout puts all 4 gates of a hid in one
// thread's regs). No gl2lds, no atomics; dispatch boundary = barrier.
__global__ __launch_bounds__(512) void lstm_step(
    const unsigned short* __restrict__ Ahi, const unsigned short* __restrict__ Alo,
    const unsigned short* __restrict__ xHi, const unsigned short* __restrict__ xLo,
    unsigned short* __restrict__ hHi0, unsigned short* __restrict__ hLo0,
    unsigned short* __restrict__ hHi1, unsigned short* __restrict__ hLo1,
    float* __restrict__ cb0, float* __restrict__ cb1,
    const float4* __restrict__ b0pk, const float4* __restrict__ b1pk, int t)
{
    __shared__ float xch[2][2][32][32];   // [src: 0=mx,1=mi][nt][row][col]
    const int tid  = threadIdx.x;
    const int wv   = tid >> 6, lane = tid & 63;
    const int mv   = wv >> 1, nt = wv & 1;
    const int hg   = blockIdx.x & 63;     // blockIdx%8 spreads hg across XCDs
    const int bg   = blockIdx.x >> 6;
    const int ml   = lane & 31, half = lane >> 5;
    const int b    = bg * 64 + nt * 32 + ml;

    int nch = 32, fbase = 0; bool act = false;
    const unsigned short *bh_p, *bl_p;
    if (mv == 0) {
        act = (t < T_ALL); nch = 8; fbase = hg * 8;
        const size_t o = ((size_t)(act ? t : 0) * 256 + b) * 128;
        bh_p = xHi + o; bl_p = xLo + o;
    } else if (mv == 1) {
        act = (t >= 1 && t < T_ALL); fbase = 512 + hg * 32;
        const size_t o = ((size_t)((t + 1) & 1) * 256 + b) * 512;
        bh_p = hHi0 + o; bl_p = hLo0 + o;
    } else if (mv == 2) {
        act = (t >= 1); fbase = 2560 + hg * 32;
        const size_t o = ((size_t)((t + 1) & 1) * 256 + b) * 512;
        bh_p = hHi0 + o; bl_p = hLo0 + o;
    } else {
        act = (t >= 2); fbase = 4608 + hg * 32;
        const size_t o = ((size_t)(t & 1) * 256 + b) * 512;   // (t-2)&1 == t&1
        bh_p = hHi1 + o; bl_p = hLo1 + o;
    }

    v16f A0, A1;
    #pragma unroll
    for (int i = 0; i < 16; ++i) { A0[i] = 0.f; A1[i] = 0.f; }

    if (act) {
        for (int c = 0; c < nch; ++c) {
            const v8s ah = *(const v8s*)(Ahi + ((size_t)(fbase + c)) * 512 + lane * 8);
            const v8s al = *(const v8s*)(Alo + ((size_t)(fbase + c)) * 512 + lane * 8);
            const v8s bh = *(const v8s*)(bh_p + c * 16 + half * 8);
            const v8s bl = *(const v8s*)(bl_p + c * 16 + half * 8);
            A0 = __builtin_amdgcn_mfma_f32_32x32x16_bf16(ah, bh, A0, 0, 0, 0);
            A1 = __builtin_amdgcn_mfma_f32_32x32x16_bf16(al, bh, A1, 0, 0, 0);
            A0 = __builtin_amdgcn_mfma_f32_32x32x16_bf16(ah, bl, A0, 0, 0, 0);
            A1 = __builtin_amdgcn_mfma_f32_32x32x16_bf16(al, bl, A1, 0, 0, 0);
        }
    }
    float av[16];
    #pragma unroll
    for (int i = 0; i < 16; ++i) av[i] = A0[i] + A1[i];

    if (mv == 0 || mv == 2) {
        const int s = mv >> 1;
        #pragma unroll
        for (int r = 0; r < 16; ++r)
            xch[s][nt][(r & 3) + 8 * (r >> 2) + 4 * half][ml] = av[r];
    }
    __syncthreads();

    if (mv == 1 && t < T_ALL) {           // layer-0 update: h0[t]
        #pragma unroll
        for (int rq = 0; rq < 4; ++rq) {
            const int hl = 2 * rq + half, hid = hg * 8 + hl;
            const float4 bs = b0pk[hid];
            float a[4];
            #pragma unroll
            for (int j = 0; j < 4; ++j)
                a[j] = av[rq * 4 + j] + xch[0][nt][j + 8 * rq + 4 * half][ml]
                     + ((const float*)&bs)[j];
            float c0 = (t > 0) ? cb0[(size_t)hid * 256 + b] : 0.f;
            const float ig = sigf(a[0]), fg = sigf(a[1]);
            const float gg = tanhf(a[2]), og = sigf(a[3]);
            c0 = fg * c0 + ig * gg;
            const float h = og * tanhf(c0);
            cb0[(size_t)hid * 256 + b] = c0;
            const size_t ho = ((size_t)(t & 1) * 256 + b) * 512 + hid;
            const unsigned short hh = f2bf(h);
            hHi0[ho] = hh;
            hLo0[ho] = f2bf(h - bf2f(hh));
        }
    }
    if (mv == 3 && t >= 1) {              // layer-1 update: h1[t-1]
        #pragma unroll
        for (int rq = 0; rq < 4; ++rq) {
            const int hl = 2 * rq + half, hid = hg * 8 + hl;
            const float4 bs = b1pk[hid];
            float a[4];
            #pragma unroll
            for (int j = 0; j < 4; ++j)
                a[j] = av[rq * 4 + j] + xch[1][nt][j + 8 * rq + 4 * half][ml]
                     + ((const float*)&bs)[j];
            float c1 = (t >= 2) ? cb1[(size_t)hid * 256 + b] : 0.f;
            const float ig = sigf(a[0]), fg = sigf(a[1]);
            const float gg = tanhf(a[2]), og = sigf(a[3]);
            c1 = fg * c1 + ig * gg;
            const float h = og * tanhf(c1);
            cb1[(size_t)hid * 256 + b] = c1;
            const size_t ho = ((size_t)((t + 1) & 1) * 256 + b) * 512 + hid;
            const unsigned short hh = f2bf(h);
            hHi1[ho] = hh;
            hLo1[ho] = f2bf(h - bf2f(hh));
        }
    }
}

// heads: base_feat = h1[:,199] (slot 1, hi+lo reconstruct) -> cls/bbox + 2 zeros
__global__ __launch_bounds__(64) void heads(
    const unsigned short* __restrict__ hHi1, const unsigned short* __restrict__ hLo1,
    const float4* __restrict__ clsW, const float* __restrict__ clsb,
    const float4* __restrict__ bbW, const float* __restrict__ bbb,
    float* __restrict__ out)
{
    const int b = blockIdx.x, j = threadIdx.x;
    const size_t off = (size_t)(256 + b) * 512;   // slot 1
    if (j < 42) {
        const float4* w = (j < 40) ? (clsW + (size_t)j * 128) : (bbW + (size_t)(j - 40) * 128);
        float acc = 0.f;
        #pragma unroll 4
        for (int k4 = 0; k4 < 128; ++k4) {
            const ushort4 hh = *(const ushort4*)(hHi1 + off + k4 * 4);
            const ushort4 hl = *(const ushort4*)(hLo1 + off + k4 * 4);
            const float4 wv = w[k4];
            acc += (bf2f(hh.x) + bf2f(hl.x)) * wv.x
                 + (bf2f(hh.y) + bf2f(hl.y)) * wv.y
                 + (bf2f(hh.z) + bf2f(hl.z)) * wv.z
                 + (bf2f(hh.w) + bf2f(hl.w)) * wv.w;
        }
        if (j < 40) out[(size_t)b * 40 + j] = acc + clsb[j];
        else        out[10240 + (size_t)b * 2 + (j - 40)] = acc + bbb[j - 40];
    }
    if (b == 0 && (j == 62 || j == 63)) out[10752 + (j - 62)] = 0.f;
}

extern "C" void kernel_launch(void* const* d_in, const int* in_sizes, int n_in,
                              void* d_out, int out_size, void* d_ws, size_t ws_size,
                              hipStream_t stream) {
    const float* proposals = (const float*)d_in[2];
    const float* Wih0 = (const float*)d_in[4];
    const float* Whh0 = (const float*)d_in[5];
    const float* bih0 = (const float*)d_in[6];
    const float* bhh0 = (const float*)d_in[7];
    const float* Wih1 = (const float*)d_in[8];
    const float* Whh1 = (const float*)d_in[9];
    const float* bih1 = (const float*)d_in[10];
    const float* bhh1 = (const float*)d_in[11];
    const float* clsW = (const float*)d_in[12];
    const float* clsb = (const float*)d_in[13];
    const float* bbW  = (const float*)d_in[14];
    const float* bbb  = (const float*)d_in[15];

    char* ws = (char*)d_ws;
    unsigned short* Ahi  = (unsigned short*)(ws + A_HI_OFF);
    unsigned short* Alo  = (unsigned short*)(ws + A_LO_OFF);
    unsigned short* xHi  = (unsigned short*)(ws + X_HI_OFF);
    unsigned short* xLo  = (unsigned short*)(ws + X_LO_OFF);
    unsigned short* hHi0 = (unsigned short*)(ws + HHI0_OFF);
    unsigned short* hLo0 = (unsigned short*)(ws + HLO0_OFF);
    unsigned short* hHi1 = (unsigned short*)(ws + HHI1_OFF);
    unsigned short* hLo1 = (unsigned short*)(ws + HLO1_OFF);
    float* cb0 = (float*)(ws + CB0_OFF);
    float* cb1 = (float*)(ws + CB1_OFF);
    float4* b0pk = (float4*)(ws + B0PK_OFF);
    float4* b1pk = (float4*)(ws + B1PK_OFF);

    pack_w<<<(int)A_FRAGS, 64, 0, stream>>>(Wih0, Whh0, Wih1, Whh1, Ahi, Alo);
    prep_x<<<200, 256, 0, stream>>>(proposals, xHi, xLo);
    pack_bias<<<1, 512, 0, stream>>>(bih0, bhh0, bih1, bhh1, b0pk, b1pk);

    for (int t = 0; t <= T_ALL; ++t)
        lstm_step<<<256, 512, 0, stream>>>(Ahi, Alo, xHi, xLo,
                                           hHi0, hLo0, hHi1, hLo1,
                                           cb0, cb1, b0pk, b1pk, t);

    heads<<<256, 64, 0, stream>>>(hHi1, hLo1, (const float4*)clsW, clsb,
                                  (const float4*)bbW, bbb, (float*)d_out);
}

// Round 11
// 4387.141 us; speedup vs baseline: 4.4133x; 1.0452x over previous
//
#include <hip/hip_runtime.h>
#include <math.h>

#define T_ALL 200

typedef __attribute__((ext_vector_type(8)))  short v8s;
typedef __attribute__((ext_vector_type(16))) float v16f;

__device__ __forceinline__ unsigned short f2bf(float f) {
    unsigned int u = __float_as_uint(f);
    u += 0x7FFF + ((u >> 16) & 1);          // round-to-nearest-even
    return (unsigned short)(u >> 16);
}
__device__ __forceinline__ float bf2f(unsigned short s) {
    return __uint_as_float(((unsigned int)s) << 16);
}
__device__ __forceinline__ float sigf(float x) { return 1.0f / (1.0f + expf(-x)); }

// ---- ws layout (bytes) ----
#define A_FRAGS   6656ULL
#define A_HI_OFF  0ULL
#define A_LO_OFF  (A_FRAGS * 1024ULL)
#define X_HI_OFF  (2ULL * A_FRAGS * 1024ULL)
#define X_BYTES   (200ULL * 256 * 128 * 2)
#define X_LO_OFF  (X_HI_OFF + X_BYTES)
#define H_BYTES   (2ULL * 256 * 512 * 2)
#define HHI0_OFF  (X_LO_OFF + X_BYTES)
#define HLO0_OFF  (HHI0_OFF + H_BYTES)
#define HHI1_OFF  (HLO0_OFF + H_BYTES)
#define HLO1_OFF  (HHI1_OFF + H_BYTES)
#define CB0_OFF   (HLO1_OFF + H_BYTES)
#define CB_BYTES  (512ULL * 256 * 4)
#define CB1_OFF   (CB0_OFF + CB_BYTES)
#define B0PK_OFF  (CB1_OFF + CB_BYTES)
#define B1PK_OFF  (B0PK_OFF + 8192ULL)

// Pack W rows into MFMA 32x32x16 A-fragment order, bf16 hi/lo planes.
// Block row order m = hl*4 + q -> global row q*512 + hg*8 + hl.
// Frag (fi, lane): A[m = lane&31][k = c*16 + (lane>>5)*8 + j], j=0..7.
__global__ __launch_bounds__(64) void pack_w(
    const float* __restrict__ Wih0, const float* __restrict__ Whh0,
    const float* __restrict__ Wih1, const float* __restrict__ Whh1,
    unsigned short* __restrict__ Ahi, unsigned short* __restrict__ Alo)
{
    const int fi = blockIdx.x, lane = threadIdx.x;
    const float* W; int K, hg, c;
    if (fi < 512)       { W = Wih0; K = 128; hg = fi >> 3;          c = fi & 7;          }
    else if (fi < 2560) { W = Whh0; K = 512; hg = (fi - 512) >> 5;  c = (fi - 512) & 31; }
    else if (fi < 4608) { W = Wih1; K = 512; hg = (fi - 2560) >> 5; c = (fi - 2560) & 31;}
    else                { W = Whh1; K = 512; hg = (fi - 4608) >> 5; c = (fi - 4608) & 31;}
    const int m = lane & 31, half = lane >> 5;
    const int q = m & 3, hl = m >> 2;
    const int r = q * 512 + hg * 8 + hl;
    const int k0 = c * 16 + half * 8;
    const float* src = W + (size_t)r * K + k0;
    unsigned short* dh = Ahi + (size_t)fi * 512 + lane * 8;
    unsigned short* dl = Alo + (size_t)fi * 512 + lane * 8;
    #pragma unroll
    for (int j = 0; j < 8; ++j) {
        const float w = src[j];
        const unsigned short h = f2bf(w);
        dh[j] = h;
        dl[j] = f2bf(w - bf2f(h));
    }
}

// proposals [b][t][c] fp32 -> xHi/xLo [t][b][c] bf16
__global__ __launch_bounds__(256) void prep_x(const float* __restrict__ prop,
                                              unsigned short* __restrict__ xHi,
                                              unsigned short* __restrict__ xLo)
{
    const int t = blockIdx.x, b = threadIdx.x;
    const float* src = prop + ((size_t)b * 200 + t) * 128;
    unsigned short* dh = xHi + ((size_t)t * 256 + b) * 128;
    unsigned short* dl = xLo + ((size_t)t * 256 + b) * 128;
    #pragma unroll 4
    for (int c = 0; c < 128; ++c) {
        const float f = src[c];
        const unsigned short h = f2bf(f);
        dh[c] = h;
        dl[c] = f2bf(f - bf2f(h));
    }
}

// bias packs: b0pk[hid] = float4 over gates (i,f,g,o)
__global__ __launch_bounds__(512) void pack_bias(
    const float* __restrict__ bih0, const float* __restrict__ bhh0,
    const float* __restrict__ bih1, const float* __restrict__ bhh1,
    float4* __restrict__ b0, float4* __restrict__ b1)
{
    const int hid = threadIdx.x;
    float4 u, v;
    u.x = bih0[hid] + bhh0[hid];
    u.y = bih0[512 + hid] + bhh0[512 + hid];
    u.z = bih0[1024 + hid] + bhh0[1024 + hid];
    u.w = bih0[1536 + hid] + bhh0[1536 + hid];
    v.x = bih1[hid] + bhh1[hid];
    v.y = bih1[512 + hid] + bhh1[512 + hid];
    v.z = bih1[1024 + hid] + bhh1[1024 + hid];
    v.w = bih1[1536 + hid] + bhh1[1536 + hid];
    b0[hid] = u; b1[hid] = v;
}

// One fused superstep per dispatch, MFMA split-bf16. 512 blocks x 256 threads
// (4 waves = 4 matvecs, one 32-batch tile per block) -> 2 blocks/CU for
// ramp/tail overlap. XCD-clustered: hg = (f&7)*8 + ((f>>3)&7) keeps 8 hgs
// (1.7 MB of fragments) per XCD. mv: 0=Wih0*x[t], 1=Whh0*h0[t-1],
// 2=Wih1*h0[t-1], 3=Whh1*h1[t-2]. mv0/mv2 C-tiles pass via LDS to mv1/mv3,
// which do the in-thread LSTM update. Dispatch boundary = barrier.
__global__ __launch_bounds__(256) void lstm_step(
    const unsigned short* __restrict__ Ahi, const unsigned short* __restrict__ Alo,
    const unsigned short* __restrict__ xHi, const unsigned short* __restrict__ xLo,
    unsigned short* __restrict__ hHi0, unsigned short* __restrict__ hLo0,
    unsigned short* __restrict__ hHi1, unsigned short* __restrict__ hLo1,
    float* __restrict__ cb0, float* __restrict__ cb1,
    const float4* __restrict__ b0pk, const float4* __restrict__ b1pk, int t)
{
    __shared__ float xch[2][32][32];      // [src: 0=mv0,1=mv2][row][col] = 8 KB
    const int tid  = threadIdx.x;
    const int mv   = tid >> 6, lane = tid & 63;
    const int f    = blockIdx.x;          // 0..511
    const int hg   = (f & 7) * 8 + ((f >> 3) & 7);   // 8 hgs per XCD
    const int bgt  = f >> 6;              // 0..7 batch tile (32 batches)
    const int ml   = lane & 31, half = lane >> 5;
    const int b    = bgt * 32 + ml;

    int nch = 32, fbase = 0; bool act = false;
    const unsigned short *bh_p, *bl_p;
    if (mv == 0) {
        act = (t < T_ALL); nch = 8; fbase = hg * 8;
        const size_t o = ((size_t)(act ? t : 0) * 256 + b) * 128;
        bh_p = xHi + o; bl_p = xLo + o;
    } else if (mv == 1) {
        act = (t >= 1 && t < T_ALL); fbase = 512 + hg * 32;
        const size_t o = ((size_t)((t + 1) & 1) * 256 + b) * 512;
        bh_p = hHi0 + o; bl_p = hLo0 + o;
    } else if (mv == 2) {
        act = (t >= 1); fbase = 2560 + hg * 32;
        const size_t o = ((size_t)((t + 1) & 1) * 256 + b) * 512;
        bh_p = hHi0 + o; bl_p = hLo0 + o;
    } else {
        act = (t >= 2); fbase = 4608 + hg * 32;
        const size_t o = ((size_t)(t & 1) * 256 + b) * 512;   // (t-2)&1 == t&1
        bh_p = hHi1 + o; bl_p = hLo1 + o;
    }

    v16f A0, A1;
    #pragma unroll
    for (int i = 0; i < 16; ++i) { A0[i] = 0.f; A1[i] = 0.f; }

    if (act) {
        for (int c = 0; c < nch; ++c) {
            const v8s ah = *(const v8s*)(Ahi + ((size_t)(fbase + c)) * 512 + lane * 8);
            const v8s al = *(const v8s*)(Alo + ((size_t)(fbase + c)) * 512 + lane * 8);
            const v8s bh = *(const v8s*)(bh_p + c * 16 + half * 8);
            const v8s bl = *(const v8s*)(bl_p + c * 16 + half * 8);
            A0 = __builtin_amdgcn_mfma_f32_32x32x16_bf16(ah, bh, A0, 0, 0, 0);
            A1 = __builtin_amdgcn_mfma_f32_32x32x16_bf16(al, bh, A1, 0, 0, 0);
            A0 = __builtin_amdgcn_mfma_f32_32x32x16_bf16(ah, bl, A0, 0, 0, 0);
            A1 = __builtin_amdgcn_mfma_f32_32x32x16_bf16(al, bl, A1, 0, 0, 0);
        }
    }
    float av[16];
    #pragma unroll
    for (int i = 0; i < 16; ++i) av[i] = A0[i] + A1[i];

    if (mv == 0 || mv == 2) {
        const int s = mv >> 1;
        #pragma unroll
        for (int r = 0; r < 16; ++r)
            xch[s][(r & 3) + 8 * (r >> 2) + 4 * half][ml] = av[r];
    }
    __syncthreads();

    if (mv == 1 && t < T_ALL) {           // layer-0 update: h0[t]
        #pragma unroll
        for (int rq = 0; rq < 4; ++rq) {
            const int hl = 2 * rq + half, hid = hg * 8 + hl;
            const float4 bs = b0pk[hid];
            float a[4];
            #pragma unroll
            for (int j = 0; j < 4; ++j)
                a[j] = av[rq * 4 + j] + xch[0][j + 8 * rq + 4 * half][ml]
                     + ((const float*)&bs)[j];
            float c0 = (t > 0) ? cb0[(size_t)hid * 256 + b] : 0.f;
            const float ig = sigf(a[0]), fg = sigf(a[1]);
            const float gg = tanhf(a[2]), og = sigf(a[3]);
            c0 = fg * c0 + ig * gg;
            const float h = og * tanhf(c0);
            cb0[(size_t)hid * 256 + b] = c0;
            const size_t ho = ((size_t)(t & 1) * 256 + b) * 512 + hid;
            const unsigned short hh = f2bf(h);
            hHi0[ho] = hh;
            hLo0[ho] = f2bf(h - bf2f(hh));
        }
    }
    if (mv == 3 && t >= 1) {              // layer-1 update: h1[t-1]
        #pragma unroll
        for (int rq = 0; rq < 4; ++rq) {
            const int hl = 2 * rq + half, hid = hg * 8 + hl;
            const float4 bs = b1pk[hid];
            float a[4];
            #pragma unroll
            for (int j = 0; j < 4; ++j)
                a[j] = av[rq * 4 + j] + xch[1][j + 8 * rq + 4 * half][ml]
                     + ((const float*)&bs)[j];
            float c1 = (t >= 2) ? cb1[(size_t)hid * 256 + b] : 0.f;
            const float ig = sigf(a[0]), fg = sigf(a[1]);
            const float gg = tanhf(a[2]), og = sigf(a[3]);
            c1 = fg * c1 + ig * gg;
            const float h = og * tanhf(c1);
            cb1[(size_t)hid * 256 + b] = c1;
            const size_t ho = ((size_t)((t + 1) & 1) * 256 + b) * 512 + hid;
            const unsigned short hh = f2bf(h);
            hHi1[ho] = hh;
            hLo1[ho] = f2bf(h - bf2f(hh));
        }
    }
}

// heads: base_feat = h1[:,199] (slot 1, hi+lo reconstruct) -> cls/bbox + 2 zeros
__global__ __launch_bounds__(64) void heads(
    const unsigned short* __restrict__ hHi1, const unsigned short* __restrict__ hLo1,
    const float4* __restrict__ clsW, const float* __restrict__ clsb,
    const float4* __restrict__ bbW, const float* __restrict__ bbb,
    float* __restrict__ out)
{
    const int b = blockIdx.x, j = threadIdx.x;
    const size_t off = (size_t)(256 + b) * 512;   // slot 1
    if (j < 42) {
        const float4* w = (j < 40) ? (clsW + (size_t)j * 128) : (bbW + (size_t)(j - 40) * 128);
        float acc = 0.f;
        #pragma unroll 4
        for (int k4 = 0; k4 < 128; ++k4) {
            const ushort4 hh = *(const ushort4*)(hHi1 + off + k4 * 4);
            const ushort4 hl = *(const ushort4*)(hLo1 + off + k4 * 4);
            const float4 wv = w[k4];
            acc += (bf2f(hh.x) + bf2f(hl.x)) * wv.x
                 + (bf2f(hh.y) + bf2f(hl.y)) * wv.y
                 + (bf2f(hh.z) + bf2f(hl.z)) * wv.z
                 + (bf2f(hh.w) + bf2f(hl.w)) * wv.w;
        }
        if (j < 40) out[(size_t)b * 40 + j] = acc + clsb[j];
        else        out[10240 + (size_t)b * 2 + (j - 40)] = acc + bbb[j - 40];
    }
    if (b == 0 && (j == 62 || j == 63)) out[10752 + (j - 62)] = 0.f;
}

extern "C" void kernel_launch(void* const* d_in, const int* in_sizes, int n_in,
                              void* d_out, int out_size, void* d_ws, size_t ws_size,
                              hipStream_t stream) {
    const float* proposals = (const float*)d_in[2];
    const float* Wih0 = (const float*)d_in[4];
    const float* Whh0 = (const float*)d_in[5];
    const float* bih0 = (const float*)d_in[6];
    const float* bhh0 = (const float*)d_in[7];
    const float* Wih1 = (const float*)d_in[8];
    const float* Whh1 = (const float*)d_in[9];
    const float* bih1 = (const float*)d_in[10];
    const float* bhh1 = (const float*)d_in[11];
    const float* clsW = (const float*)d_in[12];
    const float* clsb = (const float*)d_in[13];
    const float* bbW  = (const float*)d_in[14];
    const float* bbb  = (const float*)d_in[15];

    char* ws = (char*)d_ws;
    unsigned short* Ahi  = (unsigned short*)(ws + A_HI_OFF);
    unsigned short* Alo  = (unsigned short*)(ws + A_LO_OFF);
    unsigned short* xHi  = (unsigned short*)(ws + X_HI_OFF);
    unsigned short* xLo  = (unsigned short*)(ws + X_LO_OFF);
    unsigned short* hHi0 = (unsigned short*)(ws + HHI0_OFF);
    unsigned short* hLo0 = (unsigned short*)(ws + HLO0_OFF);
    unsigned short* hHi1 = (unsigned short*)(ws + HHI1_OFF);
    unsigned short* hLo1 = (unsigned short*)(ws + HLO1_OFF);
    float* cb0 = (float*)(ws + CB0_OFF);
    float* cb1 = (float*)(ws + CB1_OFF);
    float4* b0pk = (float4*)(ws + B0PK_OFF);
    float4* b1pk = (float4*)(ws + B1PK_OFF);

    pack_w<<<(int)A_FRAGS, 64, 0, stream>>>(Wih0, Whh0, Wih1, Whh1, Ahi, Alo);
    prep_x<<<200, 256, 0, stream>>>(proposals, xHi, xLo);
    pack_bias<<<1, 512, 0, stream>>>(bih0, bhh0, bih1, bhh1, b0pk, b1pk);

    for (int t = 0; t <= T_ALL; ++t)
        lstm_step<<<512, 256, 0, stream>>>(Ahi, Alo, xHi, xLo,
                                           hHi0, hLo0, hHi1, hLo1,
                                           cb0, cb1, b0pk, b1pk, t);

    heads<<<256, 64, 0, stream>>>(hHi1, hLo1, (const float4*)clsW, clsb,
                                  (const float4*)bbW, bbb, (float*)d_out);
}